// Round 1
// baseline (461.868 us; speedup 1.0000x reference)
//
#include <hip/hip_runtime.h>

#define T_LEN   2000
#define K_FR    400
#define K_D     400
#define A_DIM   100
#define N_ROWS  (T_LEN * K_FR)     // 800000
#define RPB     64                 // rows per tile
#define TILE_F  (RPB * A_DIM)      // 6400 floats = 25.6 KB
#define TILE_V4 (TILE_F / 4)       // 1600
#define NBATCH  (N_ROWS / RPB)     // 12500 (exact)
#define EPSF    1e-24f
#define MAIN_BLOCKS 1024

// ws layout:
//   [0,8)      double mmd_grad_acc
//   [8,408)    float  gtheta_acc[100]
//   [416,2016) float  c[400]

__global__ void mmdglm_setup(const float* __restrict__ phi_d,
                             const float* __restrict__ phi_fr,
                             float* __restrict__ c,
                             float* __restrict__ gth_acc,
                             double* __restrict__ mmdg_acc,
                             float* __restrict__ out)
{
    __shared__ float w1[8], w2[8], w3[8], w4[8];
    __shared__ float sums[4];
    const int tid = threadIdx.x;  // 512 threads
    const float vfr = (tid < K_FR) ? phi_fr[tid] : 0.f;
    const float vd  = (tid < K_D)  ? phi_d[tid]  : 0.f;
    float s1 = vfr, s2 = vfr * vfr, s3 = vd, s4 = vd * vd;
    #pragma unroll
    for (int off = 1; off < 64; off <<= 1) {
        s1 += __shfl_xor(s1, off);
        s2 += __shfl_xor(s2, off);
        s3 += __shfl_xor(s3, off);
        s4 += __shfl_xor(s4, off);
    }
    const int wave = tid >> 6, lane = tid & 63;
    if (lane == 0) { w1[wave] = s1; w2[wave] = s2; w3[wave] = s3; w4[wave] = s4; }
    __syncthreads();
    if (tid == 0) {
        float a = 0, b = 0, cc = 0, d = 0;
        for (int i = 0; i < 8; ++i) { a += w1[i]; b += w2[i]; cc += w3[i]; d += w4[i]; }
        sums[0] = a; sums[1] = b; sums[2] = cc; sums[3] = d;
    }
    __syncthreads();
    const float S_fr = sums[0], Q_fr = sums[1], S_d = sums[2], Q_d = sums[3];
    const float n_fr = (float)(K_FR * (K_FR - 1) / 2);
    const float n_d  = (float)(K_D * (K_D - 1) / 2);
    if (tid < K_FR) {
        const float p = phi_fr[tid];
        c[tid] = (S_fr * p - p * p) / n_fr
               - 2.0f * S_d * p / (float)(K_D * K_FR);
    }
    if (tid < A_DIM) gth_acc[tid] = 0.f;
    if (tid == 511) *mmdg_acc = 0.0;
    if (tid == 0) {
        const float mmd = (S_d * S_d - Q_d) / (2.0f * n_d)
                        + (S_fr * S_fr - Q_fr) / (2.0f * n_fr)
                        - 2.0f * S_d * S_fr / (float)(K_D * K_FR);
        out[101] = mmd;
    }
}

__global__ __launch_bounds__(256)
void mmdglm_main(const float* __restrict__ X,
                 const int*   __restrict__ mask,
                 const float* __restrict__ theta,
                 const float* __restrict__ tvec,
                 const float* __restrict__ c,
                 float*  __restrict__ gth_acc,
                 double* __restrict__ mmdg_acc)
{
    __shared__ __align__(16) float tile[TILE_F];
    __shared__ float lred[4];
    const int tid  = threadIdx.x;
    const int slot = tid >> 2;   // 0..63 : row within tile
    const int part = tid & 3;    // 0..3  : 25-element chunk of A

    float th[25];
    #pragma unroll
    for (int j = 0; j < 25; ++j) th[j] = theta[part * 25 + j];

    const float dt = tvec[1] - tvec[0];

    float acc[25];
    #pragma unroll
    for (int j = 0; j < 25; ++j) acc[j] = 0.f;
    float llacc = 0.f;

    for (int b = blockIdx.x; b < NBATCH; b += gridDim.x) {
        const int row0 = b * RPB;
        const float4* src = (const float4*)(X + (size_t)row0 * A_DIM);
        for (int i = tid; i < TILE_V4; i += 256)
            ((float4*)tile)[i] = src[i];
        __syncthreads();

        const int row = row0 + slot;
        const float* xp = tile + 25 * tid;   // = slot*100 + part*25
        float x[25];
        float u = 0.f;
        #pragma unroll
        for (int j = 0; j < 25; ++j) { x[j] = xp[j]; u = fmaf(x[j], th[j], u); }
        u += __shfl_xor(u, 1);
        u += __shfl_xor(u, 2);   // all 4 quad lanes now hold full dot

        const float r  = __expf(u);
        const int   m  = mask[row];
        const float ck = c[row - (row / K_FR) * K_FR];
        float w, llt;
        if (m) {
            const float eneg = __expf(-dt * r);
            const float epos = __expf(dt * r);
            llt = __logf(1.0f - eneg + EPSF);
            w   = dt * r / (epos - 1.0f - EPSF);
        } else {
            llt = -dt * r;
            w   = -dt * r;
        }
        const float cw = ck * w;
        if (part == 0) llacc = fmaf(ck, llt, llacc);
        #pragma unroll
        for (int j = 0; j < 25; ++j) acc[j] = fmaf(cw, x[j], acc[j]);
        __syncthreads();   // before next tile overwrites LDS
    }

    // ---- block reduce grad_theta: reuse tile as red[256][25] ----
    #pragma unroll
    for (int j = 0; j < 25; ++j) tile[tid * 25 + j] = acc[j];
    __syncthreads();
    if (tid < A_DIM) {
        const int p = tid / 25, j = tid - p * 25;   // a = p*25 + j
        float s = 0.f;
        for (int sl = 0; sl < RPB; ++sl)
            s += tile[(sl * 4 + p) * 25 + j];
        atomicAdd(&gth_acc[tid], s);
    }

    // ---- block reduce mmd_grad partial ----
    float l = llacc;
    #pragma unroll
    for (int off = 1; off < 64; off <<= 1) l += __shfl_xor(l, off);
    const int wave = tid >> 6, lane = tid & 63;
    if (lane == 0) lred[wave] = l;
    __syncthreads();
    if (tid == 0)
        atomicAdd(mmdg_acc, (double)(lred[0] + lred[1] + lred[2] + lred[3]));
}

__global__ void mmdglm_finalize(const double* __restrict__ mmdg_acc,
                                const float* __restrict__ gth_acc,
                                float* __restrict__ out)
{
    const int tid = threadIdx.x;
    if (tid == 0) out[0] = (float)(*mmdg_acc);
    if (tid >= 1 && tid <= 100) out[tid] = gth_acc[tid - 1];
}

extern "C" void kernel_launch(void* const* d_in, const int* in_sizes, int n_in,
                              void* d_out, int out_size, void* d_ws, size_t ws_size,
                              hipStream_t stream) {
    const float* t      = (const float*)d_in[0];
    const int*   mask   = (const int*)  d_in[1];
    const float* X      = (const float*)d_in[2];
    const float* theta  = (const float*)d_in[3];
    const float* phi_d  = (const float*)d_in[4];
    const float* phi_fr = (const float*)d_in[5];
    float* out = (float*)d_out;

    char* ws = (char*)d_ws;
    double* mmdg_acc = (double*)ws;
    float*  gth_acc  = (float*)(ws + 8);
    float*  c        = (float*)(ws + 416);

    mmdglm_setup<<<1, 512, 0, stream>>>(phi_d, phi_fr, c, gth_acc, mmdg_acc, out);
    mmdglm_main<<<MAIN_BLOCKS, 256, 0, stream>>>(X, mask, theta, t, c, gth_acc, mmdg_acc);
    mmdglm_finalize<<<1, 128, 0, stream>>>(mmdg_acc, gth_acc, out);
}